// Round 6
// baseline (509.948 us; speedup 1.0000x reference)
//
#include <hip/hip_runtime.h>
#include <hip/hip_cooperative_groups.h>

namespace cg = cooperative_groups;

#define N_NODES 50000
#define N_EDGES 600000
#define D 128
#define CAP 64   // fixed-capacity neighbor rows; P(deg>64) ~ 1e-26 here; spill path keeps correctness for any input
#define NTILES (N_NODES / 16)   // 3125
#define SCAN_BLOCKS ((N_NODES + 255) / 256)

typedef __attribute__((ext_vector_type(8))) short bf16x8;
typedef __attribute__((ext_vector_type(4))) float floatx4;

__device__ inline unsigned int f2bf(float f) {
    unsigned int u = __float_as_uint(f);
    return (u + 0x7FFFu + ((u >> 16) & 1u)) >> 16;   // RNE
}
__device__ inline float bf_lo(unsigned int u) { return __uint_as_float(u << 16); }
__device__ inline float bf_hi(unsigned int u) { return __uint_as_float(u & 0xFFFF0000u); }

#define ACC8(vv) do { \
    acc[0] += bf_lo((vv).x); acc[1] += bf_hi((vv).x); \
    acc[2] += bf_lo((vv).y); acc[3] += bf_hi((vv).y); \
    acc[4] += bf_lo((vv).z); acc[5] += bf_hi((vv).z); \
    acc[6] += bf_lo((vv).w); acc[7] += bf_hi((vv).w); } while (0)

// ---- one 16-node tile: gather-mean + MFMA (verbatim R2 structure, proven) ----
template <bool RELU, bool OUT_BF16>
__device__ void layer_tile(int tileId, unsigned short (*tile)[136],
                           const int* __restrict__ cnt, const unsigned short* __restrict__ buf,
                           const int* __restrict__ spillN, const int* __restrict__ spillD,
                           const int* __restrict__ spillS,
                           const unsigned short* __restrict__ Xbf,
                           const unsigned short* __restrict__ Wlbf, const float* __restrict__ bias,
                           const unsigned short* __restrict__ Wrbf, void* __restrict__ outp) {
    const int t = threadIdx.x;
    const int node0 = tileId * 16;

    // ---- phase 1: gather mean ----
    {
        const int nl = t >> 4, q = t & 15;
        const int node = node0 + nl;
        const int deg = cnt[node];
        const int m = deg < CAP ? deg : CAP;
        const unsigned short* __restrict__ nb = buf + (size_t)node * CAP;
        float acc[8] = {0.f, 0.f, 0.f, 0.f, 0.f, 0.f, 0.f, 0.f};
        int e = 0;
        for (; e + 8 <= m; e += 8) {
            uint4 v[8];
#pragma unroll
            for (int u = 0; u < 8; ++u)
                v[u] = *(const uint4*)(Xbf + (size_t)nb[e + u] * D + q * 8);
#pragma unroll
            for (int u = 0; u < 8; ++u) ACC8(v[u]);
        }
        for (; e + 4 <= m; e += 4) {
            uint4 v[4];
#pragma unroll
            for (int u = 0; u < 4; ++u)
                v[u] = *(const uint4*)(Xbf + (size_t)nb[e + u] * D + q * 8);
#pragma unroll
            for (int u = 0; u < 4; ++u) ACC8(v[u]);
        }
        for (; e < m; ++e) {
            uint4 v = *(const uint4*)(Xbf + (size_t)nb[e] * D + q * 8);
            ACC8(v);
        }
        if (deg > CAP) {                       // correctness-only path; never taken for this graph
            int sn = *spillN;
            for (int k = 0; k < sn; ++k) {
                if (spillD[k] == node) {
                    uint4 v = *(const uint4*)(Xbf + (size_t)spillS[k] * D + q * 8);
                    ACC8(v);
                }
            }
        }
        float inv = (deg > 0) ? 1.0f / (float)deg : 0.0f;
        uint4 o;
        o.x = f2bf(acc[0] * inv) | (f2bf(acc[1] * inv) << 16);
        o.y = f2bf(acc[2] * inv) | (f2bf(acc[3] * inv) << 16);
        o.z = f2bf(acc[4] * inv) | (f2bf(acc[5] * inv) << 16);
        o.w = f2bf(acc[6] * inv) | (f2bf(acc[7] * inv) << 16);
        *(uint4*)(&tile[nl][q * 8]) = o;
    }
    __syncthreads();

    // ---- phase 2: MFMA ----
    {
        const int lane = t & 63;
        const int wv = t >> 6;                 // wave id 0..3 -> feats [32wv, 32wv+32)
        const int l15 = lane & 15;
        const int quad = lane >> 4;

        floatx4 c0 = (floatx4)(0.f), c1 = (floatx4)(0.f);
        const int nf0 = wv * 2, nf1 = wv * 2 + 1;

        const unsigned short* mrow = &tile[l15][quad * 8];
        const unsigned short* arowX = Xbf + (size_t)(node0 + l15) * D + quad * 8;

#pragma unroll
        for (int kk = 0; kk < 4; ++kk) {
            bf16x8 a = *(const bf16x8*)(mrow + kk * 32);
            bf16x8 b0 = *(const bf16x8*)(Wlbf + (size_t)(nf0 * 16 + l15) * D + kk * 32 + quad * 8);
            bf16x8 b1 = *(const bf16x8*)(Wlbf + (size_t)(nf1 * 16 + l15) * D + kk * 32 + quad * 8);
            c0 = __builtin_amdgcn_mfma_f32_16x16x32_bf16(a, b0, c0, 0, 0, 0);
            c1 = __builtin_amdgcn_mfma_f32_16x16x32_bf16(a, b1, c1, 0, 0, 0);
        }
#pragma unroll
        for (int kk = 0; kk < 4; ++kk) {
            bf16x8 a = *(const bf16x8*)(arowX + kk * 32);
            bf16x8 b0 = *(const bf16x8*)(Wrbf + (size_t)(nf0 * 16 + l15) * D + kk * 32 + quad * 8);
            bf16x8 b1 = *(const bf16x8*)(Wrbf + (size_t)(nf1 * 16 + l15) * D + kk * 32 + quad * 8);
            c0 = __builtin_amdgcn_mfma_f32_16x16x32_bf16(a, b0, c0, 0, 0, 0);
            c1 = __builtin_amdgcn_mfma_f32_16x16x32_bf16(a, b1, c1, 0, 0, 0);
        }

#pragma unroll
        for (int j = 0; j < 2; ++j) {
            floatx4 c = j ? c1 : c0;
            int f = (wv * 2 + j) * 16 + l15;
            float bv = bias[f];
#pragma unroll
            for (int r = 0; r < 4; ++r) {
                float v = c[r] + bv;
                if (RELU) v = v > 0.f ? v : 0.2f * v;
                int node = node0 + quad * 4 + r;
                if (OUT_BF16)
                    ((unsigned short*)outp)[(size_t)node * D + f] = (unsigned short)f2bf(v);
                else
                    ((float*)outp)[(size_t)node * D + f] = v;
            }
        }
    }
    __syncthreads();   // tile LDS reused by next grid-stride iteration
}

// ---- single fused cooperative kernel: zero -> prep -> layer1 -> layer2 ----
// NOTE: xbf aliases out (both live in d_out) -> neither is __restrict__.
__global__ void __launch_bounds__(256, 8) k_fused(
    const float* __restrict__ x, const int* __restrict__ src, const int* __restrict__ dst,
    const float* __restrict__ W1l, const float* __restrict__ b1, const float* __restrict__ W1r,
    const float* __restrict__ W2l, const float* __restrict__ b2, const float* __restrict__ W2r,
    int* __restrict__ cnt, unsigned short* __restrict__ buf,
    int* __restrict__ spillN, int* __restrict__ spillD, int* __restrict__ spillS,
    unsigned short* __restrict__ wbf, unsigned short* xbf,
    unsigned short* __restrict__ hbf, float* out) {
    __shared__ unsigned short tile[16][136];   // 272 B row stride (16B-mult)

    cg::grid_group grid = cg::this_grid();
    const int t = threadIdx.x;
    const int gid = blockIdx.x * 256 + t;
    const int gsz = gridDim.x * 256;

    // ---- P0: zero counters (replaces hipMemsetAsync dispatch) ----
    for (int i = gid; i < N_NODES; i += gsz) cnt[i] = 0;
    if (gid == 0) *spillN = 0;
    __threadfence();
    grid.sync();
    __threadfence();

    // ---- P1: edge bucketing + x cvt + W cvt ----
    for (int e = gid; e < N_EDGES; e += gsz) {
        int d = dst[e], s = src[e];
        int p = atomicAdd(&cnt[d], 1);
        if (p < CAP) {
            buf[(size_t)d * CAP + p] = (unsigned short)s;   // src < 50000 fits u16
        } else {
            int k = atomicAdd(spillN, 1);
            spillD[k] = d; spillS[k] = s;
        }
    }
    for (int i = gid; i < N_NODES * D / 4; i += gsz) {
        float4 v = ((const float4*)x)[i];
        uint2 o;
        o.x = f2bf(v.x) | (f2bf(v.y) << 16);
        o.y = f2bf(v.z) | (f2bf(v.w) << 16);
        ((uint2*)xbf)[i] = o;
    }
    for (int i = gid; i < 4 * D * D; i += gsz) {
        int wsel = i >> 14, idx = i & 16383;
        const float* p = wsel == 0 ? W1l : wsel == 1 ? W1r : wsel == 2 ? W2l : W2r;
        wbf[i] = (unsigned short)f2bf(p[idx]);
    }
    __threadfence();
    grid.sync();
    __threadfence();

    // ---- P2: layer 1 (x -> hbf, leaky-relu, bf16 out) ----
    for (int tl = blockIdx.x; tl < NTILES; tl += gridDim.x)
        layer_tile<true, true>(tl, tile, cnt, buf, spillN, spillD, spillS,
                               xbf, wbf, b1, wbf + 16384, (void*)hbf);
    __threadfence();
    grid.sync();
    __threadfence();

    // ---- P3: layer 2 (hbf -> out, fp32) ----
    for (int tl = blockIdx.x; tl < NTILES; tl += gridDim.x)
        layer_tile<false, false>(tl, tile, cnt, buf, spillN, spillD, spillS,
                                 hbf, wbf + 32768, b2, wbf + 49152, (void*)out);
}

// ---------------- fallback path (proven R2 kernels, 223.7 us) ----------------

__global__ void k_prep(const float* __restrict__ x, unsigned short* __restrict__ xbf,
                       const float* __restrict__ wa, const float* __restrict__ wb,
                       const float* __restrict__ wc, const float* __restrict__ wd,
                       unsigned short* __restrict__ wbf,
                       const int* __restrict__ src, const int* __restrict__ dst,
                       int* __restrict__ cnt, unsigned short* __restrict__ buf,
                       int* __restrict__ spillN, int* __restrict__ spillD,
                       int* __restrict__ spillS) {
    const int b = blockIdx.x;
    const int t = threadIdx.x;
    if (b < 2344) {
        int e = b * 256 + t;
        if (e < N_EDGES) {
            int d = dst[e], s = src[e];
            int p = atomicAdd(&cnt[d], 1);
            if (p < CAP) {
                buf[(size_t)d * CAP + p] = (unsigned short)s;
            } else {
                int k = atomicAdd(spillN, 1);
                spillD[k] = d; spillS[k] = s;
            }
        }
    } else if (b < 8594) {
        int i = (b - 2344) * 256 + t;
        float4 v = ((const float4*)x)[i];
        uint2 o;
        o.x = f2bf(v.x) | (f2bf(v.y) << 16);
        o.y = f2bf(v.z) | (f2bf(v.w) << 16);
        ((uint2*)xbf)[i] = o;
    } else {
        int i = (b - 8594) * 256 + t;
        const float* srcs[4] = {wa, wb, wc, wd};
        wbf[i] = (unsigned short)f2bf(srcs[i >> 14][i & 16383]);
    }
}

template <bool RELU, bool OUT_BF16>
__global__ void __launch_bounds__(256) k_gather_layer(
    const int* __restrict__ cnt, const unsigned short* __restrict__ buf,
    const int* __restrict__ spillN, const int* __restrict__ spillD,
    const int* __restrict__ spillS,
    const unsigned short* __restrict__ Xbf,
    const unsigned short* __restrict__ Wlbf, const float* __restrict__ bias,
    const unsigned short* __restrict__ Wrbf, void* __restrict__ outp) {
    __shared__ unsigned short tile[16][136];
    layer_tile<RELU, OUT_BF16>(blockIdx.x, tile, cnt, buf, spillN, spillD, spillS,
                               Xbf, Wlbf, bias, Wrbf, outp);
}

// ---------------- host launch ----------------

extern "C" void kernel_launch(void* const* d_in, const int* in_sizes, int n_in,
                              void* d_out, int out_size, void* d_ws, size_t ws_size,
                              hipStream_t stream) {
    (void)in_sizes; (void)n_in; (void)out_size; (void)ws_size;

    const float* x   = (const float*)d_in[0];
    const int*   ei  = (const int*)d_in[1];
    const float* W1l = (const float*)d_in[2];
    const float* b1  = (const float*)d_in[3];
    const float* W1r = (const float*)d_in[4];
    const float* W2l = (const float*)d_in[5];
    const float* b2  = (const float*)d_in[6];
    const float* W2r = (const float*)d_in[7];

    const int* src = ei;
    const int* dst = ei + N_EDGES;

    char* ws = (char*)d_ws;
    int* cnt              = (int*)(ws + 0);                  // 200,000 B
    int* spillN           = (int*)(ws + 200000);             // 4 B
    int* spillD           = (int*)(ws + 200064);             // 2,400,000 B
    int* spillS           = (int*)(ws + 2600064);            // 2,400,000 B
    unsigned short* buf   = (unsigned short*)(ws + 5000064); // 6,400,000 B (50000*64 u16)
    unsigned short* wbf   = (unsigned short*)(ws + 11400064);// 131,072 B
    unsigned short* hbf   = (unsigned short*)(ws + 11531136);// 12,800,000 B  (ends 24.3 MB)

    // xbf lives in d_out (25.6 MB): layer 2 never reads x, so the final fp32
    // output write may clobber it.
    unsigned short* xbf = (unsigned short*)d_out;
    float* out = (float*)d_out;

    // ---- size the cooperative grid from the runtime's own occupancy calc ----
    static int coopBlocks = -2;   // -2 = uncomputed, -1 = unavailable
    if (coopBlocks == -2) {
        int perCU = 0, nCU = 0, dev = 0;
        if (hipGetDevice(&dev) == hipSuccess &&
            hipOccupancyMaxActiveBlocksPerMultiprocessor(&perCU, (const void*)k_fused,
                                                         256, 0) == hipSuccess &&
            hipDeviceGetAttribute(&nCU, hipDeviceAttributeMultiprocessorCount,
                                  dev) == hipSuccess &&
            perCU > 0 && nCU > 0) {
            long long cap = (long long)perCU * (long long)nCU;
            coopBlocks = (int)(cap < 2048 ? cap : 2048);
        } else {
            coopBlocks = -1;
        }
    }

    bool done = false;
    if (coopBlocks > 0) {
        void* args[] = {
            (void*)&x, (void*)&src, (void*)&dst,
            (void*)&W1l, (void*)&b1, (void*)&W1r,
            (void*)&W2l, (void*)&b2, (void*)&W2r,
            (void*)&cnt, (void*)&buf,
            (void*)&spillN, (void*)&spillD, (void*)&spillS,
            (void*)&wbf, (void*)&xbf, (void*)&hbf, (void*)&out,
        };
        hipError_t err = hipLaunchCooperativeKernel((const void*)k_fused,
                                                    dim3(coopBlocks), dim3(256),
                                                    args, 0, stream);
        if (err == hipSuccess) {
            done = true;
        } else {
            (void)hipGetLastError();   // clear sticky error before fallback
        }
    }

    if (!done) {
        // proven 4-dispatch path (R2: 223.7 us)
        hipMemsetAsync(ws, 0, 200064, stream);
        k_prep<<<8850, 256, 0, stream>>>(x, xbf, W1l, W1r, W2l, W2r, wbf,
                                         src, dst, cnt, buf, spillN, spillD, spillS);
        k_gather_layer<true, true><<<NTILES, 256, 0, stream>>>(
            cnt, buf, spillN, spillD, spillS, xbf, wbf, b1, wbf + 16384, (void*)hbf);
        k_gather_layer<false, false><<<NTILES, 256, 0, stream>>>(
            cnt, buf, spillN, spillD, spillS, hbf, wbf + 32768, b2, wbf + 49152, (void*)out);
    }
}

// Round 7
// 223.153 us; speedup vs baseline: 2.2852x; 2.2852x over previous
//
#include <hip/hip_runtime.h>

#define N_NODES 50000
#define N_EDGES 600000
#define D 128
#define CAP 64   // fixed-capacity neighbor rows; P(deg>64) ~ 1e-26 here; spill path keeps correctness for any input
#define NTILES (N_NODES / 16)   // 3125

typedef __attribute__((ext_vector_type(8))) short bf16x8;
typedef __attribute__((ext_vector_type(4))) float floatx4;

__device__ inline unsigned int f2bf(float f) {
    unsigned int u = __float_as_uint(f);
    return (u + 0x7FFFu + ((u >> 16) & 1u)) >> 16;   // RNE
}
__device__ inline float bf_lo(unsigned int u) { return __uint_as_float(u << 16); }
__device__ inline float bf_hi(unsigned int u) { return __uint_as_float(u & 0xFFFF0000u); }

// ---------------- fused prep: edge bucketing + cvt x -> bf16 + cvt W -> bf16 ----
// blocks [0,586): edge bucketing, 4 edges/thread via int4 loads, 4 interleaved
//   atomic->store chains per lane (ILP on the scatter's dependent latency)
// blocks [586,6836): x conversion (1 float4/thread) -> xbf (lives in d_out)
// blocks [6836,7092): weight conversion (4 * 128*128 elems)
__global__ void k_prep(const float* __restrict__ x, unsigned short* __restrict__ xbf,
                       const float* __restrict__ wa, const float* __restrict__ wb,
                       const float* __restrict__ wc, const float* __restrict__ wd,
                       unsigned short* __restrict__ wbf,
                       const int* __restrict__ src, const int* __restrict__ dst,
                       int* __restrict__ cnt, unsigned short* __restrict__ buf,
                       int* __restrict__ spillN, int* __restrict__ spillD,
                       int* __restrict__ spillS) {
    const int b = blockIdx.x;
    const int t = threadIdx.x;
    if (b < 586) {
        int idx = b * 256 + t;                 // quad-edge index
        if (idx * 4 < N_EDGES) {               // N_EDGES % 4 == 0 -> full int4 always
            int4 dv = ((const int4*)dst)[idx];
            int4 sv = ((const int4*)src)[idx];
            // 4 independent atomic chains issued together
            int p0 = atomicAdd(&cnt[dv.x], 1);
            int p1 = atomicAdd(&cnt[dv.y], 1);
            int p2 = atomicAdd(&cnt[dv.z], 1);
            int p3 = atomicAdd(&cnt[dv.w], 1);
            if (p0 < CAP) buf[(size_t)dv.x * CAP + p0] = (unsigned short)sv.x;
            else { int k = atomicAdd(spillN, 1); spillD[k] = dv.x; spillS[k] = sv.x; }
            if (p1 < CAP) buf[(size_t)dv.y * CAP + p1] = (unsigned short)sv.y;
            else { int k = atomicAdd(spillN, 1); spillD[k] = dv.y; spillS[k] = sv.y; }
            if (p2 < CAP) buf[(size_t)dv.z * CAP + p2] = (unsigned short)sv.z;
            else { int k = atomicAdd(spillN, 1); spillD[k] = dv.z; spillS[k] = sv.z; }
            if (p3 < CAP) buf[(size_t)dv.w * CAP + p3] = (unsigned short)sv.w;
            else { int k = atomicAdd(spillN, 1); spillD[k] = dv.w; spillS[k] = sv.w; }
        }
    } else if (b < 6836) {
        int i = (b - 586) * 256 + t;
        float4 v = ((const float4*)x)[i];
        uint2 o;
        o.x = f2bf(v.x) | (f2bf(v.y) << 16);
        o.y = f2bf(v.z) | (f2bf(v.w) << 16);
        ((uint2*)xbf)[i] = o;
    } else {
        int i = (b - 6836) * 256 + t;
        const float* srcs[4] = {wa, wb, wc, wd};
        wbf[i] = (unsigned short)f2bf(srcs[i >> 14][i & 16383]);
    }
}

// ---------------- fused gather + MFMA layer (verbatim R2, proven 52.9us) ----
// Block = 256 threads = 16 nodes.
// Phase 1 (gather): thread (nl=t>>4, q=t&15) accumulates mean of node node0+nl,
//   cols [8q, 8q+8) in fp32; 16 consecutive lanes/node -> coalesced 256 B row
//   reads. 8-deep unroll: 8 independent uint4 row loads in flight per lane.
// Phase 2 (MFMA): wave wv computes feats [32*wv, 32*wv+32) for the 16 nodes.
//   A: lane=(l15,quad) -> row l15, k = quad*8 + kk*32 ; C/D: col=l15, row=quad*4+r.
#define ACC8(vv) do { \
    acc[0] += bf_lo((vv).x); acc[1] += bf_hi((vv).x); \
    acc[2] += bf_lo((vv).y); acc[3] += bf_hi((vv).y); \
    acc[4] += bf_lo((vv).z); acc[5] += bf_hi((vv).z); \
    acc[6] += bf_lo((vv).w); acc[7] += bf_hi((vv).w); } while (0)

template <bool RELU, bool OUT_BF16>
__global__ void __launch_bounds__(256) k_gather_layer(
    const int* __restrict__ cnt, const unsigned short* __restrict__ buf,
    const int* __restrict__ spillN, const int* __restrict__ spillD,
    const int* __restrict__ spillS,
    const unsigned short* __restrict__ Xbf,
    const unsigned short* __restrict__ Wlbf, const float* __restrict__ bias,
    const unsigned short* __restrict__ Wrbf, void* __restrict__ outp) {
    __shared__ unsigned short tile[16][136];   // 272 B row stride (16B-mult)

    const int t = threadIdx.x;
    const int node0 = blockIdx.x * 16;         // grid 3125 -> exact

    // ---- phase 1: gather mean ----
    {
        const int nl = t >> 4, q = t & 15;
        const int node = node0 + nl;
        const int deg = cnt[node];
        const int m = deg < CAP ? deg : CAP;
        const unsigned short* __restrict__ nb = buf + (size_t)node * CAP;
        float acc[8] = {0.f, 0.f, 0.f, 0.f, 0.f, 0.f, 0.f, 0.f};
        int e = 0;
        for (; e + 8 <= m; e += 8) {
            uint4 v[8];
#pragma unroll
            for (int u = 0; u < 8; ++u)
                v[u] = *(const uint4*)(Xbf + (size_t)nb[e + u] * D + q * 8);
#pragma unroll
            for (int u = 0; u < 8; ++u) ACC8(v[u]);
        }
        for (; e + 4 <= m; e += 4) {
            uint4 v[4];
#pragma unroll
            for (int u = 0; u < 4; ++u)
                v[u] = *(const uint4*)(Xbf + (size_t)nb[e + u] * D + q * 8);
#pragma unroll
            for (int u = 0; u < 4; ++u) ACC8(v[u]);
        }
        for (; e < m; ++e) {
            uint4 v = *(const uint4*)(Xbf + (size_t)nb[e] * D + q * 8);
            ACC8(v);
        }
        if (deg > CAP) {                       // correctness-only path; never taken for this graph
            int sn = *spillN;
            for (int k = 0; k < sn; ++k) {
                if (spillD[k] == node) {
                    uint4 v = *(const uint4*)(Xbf + (size_t)spillS[k] * D + q * 8);
                    ACC8(v);
                }
            }
        }
        float inv = (deg > 0) ? 1.0f / (float)deg : 0.0f;
        uint4 o;
        o.x = f2bf(acc[0] * inv) | (f2bf(acc[1] * inv) << 16);
        o.y = f2bf(acc[2] * inv) | (f2bf(acc[3] * inv) << 16);
        o.z = f2bf(acc[4] * inv) | (f2bf(acc[5] * inv) << 16);
        o.w = f2bf(acc[6] * inv) | (f2bf(acc[7] * inv) << 16);
        *(uint4*)(&tile[nl][q * 8]) = o;
    }
    __syncthreads();

    // ---- phase 2: MFMA ----
    const int lane = t & 63;
    const int wv = t >> 6;                 // wave id 0..3 -> feats [32wv, 32wv+32)
    const int l15 = lane & 15;
    const int quad = lane >> 4;

    floatx4 c0 = (floatx4)(0.f), c1 = (floatx4)(0.f);
    const int nf0 = wv * 2, nf1 = wv * 2 + 1;

    const unsigned short* mrow = &tile[l15][quad * 8];
    const unsigned short* arowX = Xbf + (size_t)(node0 + l15) * D + quad * 8;

#pragma unroll
    for (int kk = 0; kk < 4; ++kk) {
        bf16x8 a = *(const bf16x8*)(mrow + kk * 32);
        bf16x8 b0 = *(const bf16x8*)(Wlbf + (size_t)(nf0 * 16 + l15) * D + kk * 32 + quad * 8);
        bf16x8 b1 = *(const bf16x8*)(Wlbf + (size_t)(nf1 * 16 + l15) * D + kk * 32 + quad * 8);
        c0 = __builtin_amdgcn_mfma_f32_16x16x32_bf16(a, b0, c0, 0, 0, 0);
        c1 = __builtin_amdgcn_mfma_f32_16x16x32_bf16(a, b1, c1, 0, 0, 0);
    }
#pragma unroll
    for (int kk = 0; kk < 4; ++kk) {
        bf16x8 a = *(const bf16x8*)(arowX + kk * 32);
        bf16x8 b0 = *(const bf16x8*)(Wrbf + (size_t)(nf0 * 16 + l15) * D + kk * 32 + quad * 8);
        bf16x8 b1 = *(const bf16x8*)(Wrbf + (size_t)(nf1 * 16 + l15) * D + kk * 32 + quad * 8);
        c0 = __builtin_amdgcn_mfma_f32_16x16x32_bf16(a, b0, c0, 0, 0, 0);
        c1 = __builtin_amdgcn_mfma_f32_16x16x32_bf16(a, b1, c1, 0, 0, 0);
    }

#pragma unroll
    for (int j = 0; j < 2; ++j) {
        floatx4 c = j ? c1 : c0;
        int f = (wv * 2 + j) * 16 + l15;
        float bv = bias[f];
#pragma unroll
        for (int r = 0; r < 4; ++r) {
            float v = c[r] + bv;
            if (RELU) v = v > 0.f ? v : 0.2f * v;
            int node = node0 + quad * 4 + r;
            if (OUT_BF16)
                ((unsigned short*)outp)[(size_t)node * D + f] = (unsigned short)f2bf(v);
            else
                ((float*)outp)[(size_t)node * D + f] = v;
        }
    }
}

// ---------------- host launch ----------------

extern "C" void kernel_launch(void* const* d_in, const int* in_sizes, int n_in,
                              void* d_out, int out_size, void* d_ws, size_t ws_size,
                              hipStream_t stream) {
    (void)in_sizes; (void)n_in; (void)out_size; (void)ws_size;

    const float* x   = (const float*)d_in[0];
    const int*   ei  = (const int*)d_in[1];
    const float* W1l = (const float*)d_in[2];
    const float* b1  = (const float*)d_in[3];
    const float* W1r = (const float*)d_in[4];
    const float* W2l = (const float*)d_in[5];
    const float* b2  = (const float*)d_in[6];
    const float* W2r = (const float*)d_in[7];

    const int* src = ei;
    const int* dst = ei + N_EDGES;

    char* ws = (char*)d_ws;
    int* cnt              = (int*)(ws + 0);                  // 200,000 B
    int* spillN           = (int*)(ws + 200000);             // 4 B (zeroed with cnt)
    int* spillD           = (int*)(ws + 200064);             // 2,400,000 B
    int* spillS           = (int*)(ws + 2600064);            // 2,400,000 B
    unsigned short* buf   = (unsigned short*)(ws + 5000064); // 6,400,000 B (50000*64 u16)
    unsigned short* wbf   = (unsigned short*)(ws + 11400064);// 131,072 B
    unsigned short* hbf   = (unsigned short*)(ws + 11531136);// 12,800,000 B  (ends 24.3 MB)

    // xbf lives in d_out (25.6 MB): layer 2 never reads x, so the final fp32
    // output write may clobber it.
    unsigned short* xbf = (unsigned short*)d_out;
    float* out = (float*)d_out;

    unsigned short* w1l_bf = wbf;
    unsigned short* w1r_bf = wbf + 16384;
    unsigned short* w2l_bf = wbf + 32768;
    unsigned short* w2r_bf = wbf + 49152;

    hipMemsetAsync(ws, 0, 200064, stream);   // cnt + spillN

    k_prep<<<7092, 256, 0, stream>>>(x, xbf, W1l, W1r, W2l, W2r, wbf,
                                     src, dst, cnt, buf, spillN, spillD, spillS);

    k_gather_layer<true, true><<<NTILES, 256, 0, stream>>>(
        cnt, buf, spillN, spillD, spillS, xbf, w1l_bf, b1, w1r_bf, (void*)hbf);
    k_gather_layer<false, false><<<NTILES, 256, 0, stream>>>(
        cnt, buf, spillN, spillD, spillS, hbf, w2l_bf, b2, w2r_bf, (void*)out);
}